// Round 1
// baseline (672.070 us; speedup 1.0000x reference)
//
#include <hip/hip_runtime.h>
#include <hip/hip_bf16.h>
#include <stdint.h>

#define R_ 32
#define H_ 256
#define GAMMA_ 10.0f

typedef __attribute__((ext_vector_type(4))) float f32x4;
typedef __attribute__((ext_vector_type(8))) short bf16x8;

__device__ __forceinline__ unsigned short f2b(float f){
  union { float f; unsigned u; } v; v.f = f;
  unsigned r = v.u + 0x7FFFu + ((v.u >> 16) & 1u);
  return (unsigned short)(r >> 16);
}
__device__ __forceinline__ float b2f(unsigned short h){
  union { unsigned u; float f; } v; v.u = ((unsigned)h) << 16; return v.f;
}

// ---------- fp32 -> bf16 convert (vectorized) ----------
__global__ void cvt_kernel(const float* __restrict__ in, unsigned short* __restrict__ out, int n4){
  int i = blockIdx.x * 256 + threadIdx.x;
  if (i < n4){
    float4 v = ((const float4*)in)[i];
    ushort4 o; o.x=f2b(v.x); o.y=f2b(v.y); o.z=f2b(v.z); o.w=f2b(v.w);
    ((ushort4*)out)[i] = o;
  }
}

// ---------- transpose [256][256] fp32 -> [256][256] bf16 (per z-slice) ----------
__global__ void transw_kernel(const float* __restrict__ W, unsigned short* __restrict__ Wt){
  __shared__ float tile[32][33];
  int r = blockIdx.z;
  int i0 = blockIdx.x * 32, o0 = blockIdx.y * 32;
  const float* Wr = W + (size_t)r * 65536;
  for (int rr = threadIdx.y; rr < 32; rr += 8)
    tile[rr][threadIdx.x] = Wr[(size_t)(i0 + rr) * 256 + o0 + threadIdx.x];
  __syncthreads();
  unsigned short* Wtr = Wt + (size_t)r * 65536;
  for (int rr = threadIdx.y; rr < 32; rr += 8)
    Wtr[(size_t)(o0 + rr) * 256 + i0 + threadIdx.x] = f2b(tile[threadIdx.x][rr]);
}

// ---------- wq[r][i] = sum_o W[r][i][o]*q[r][o]; wk likewise ----------
__global__ void wqk_kernel(const float* __restrict__ W, const float* __restrict__ q,
                           const float* __restrict__ k, float* __restrict__ wq, float* __restrict__ wk){
  int i = blockIdx.x, r = blockIdx.y, lane = threadIdx.x;
  const float* row = W + ((size_t)r * 256 + i) * 256;
  float sq = 0.f, sk = 0.f;
  for (int o = lane; o < 256; o += 64){ float w = row[o]; sq += w * q[r*256+o]; sk += w * k[r*256+o]; }
  #pragma unroll
  for (int off = 32; off; off >>= 1){ sq += __shfl_xor(sq, off); sk += __shfl_xor(sk, off); }
  if (!lane){ wq[r*256+i] = sq; wk[r*256+i] = sk; }
}

// ---------- rel = relu(rel_bert @ rel_lin_w + b) -> bf16 [32][256] ----------
__global__ void rel_kernel(const float* __restrict__ rb, const float* __restrict__ rw,
                           const float* __restrict__ bias, unsigned short* __restrict__ relb){
  int r = blockIdx.x, h = threadIdx.x;
  float acc = bias[h];
  const float* br = rb + (size_t)r * 768;
  for (int i = 0; i < 768; ++i) acc += br[i] * rw[(size_t)i * 256 + h];
  relb[r*256 + h] = f2b(fmaxf(acc, 0.f));
}

// ---------- CSR build ----------
__global__ void hist_kernel(const int* __restrict__ dst, int* __restrict__ deg, int E){
  int e = blockIdx.x * 256 + threadIdx.x;
  if (e < E) atomicAdd(&deg[dst[e]], 1);
}
__global__ void scan_kernel(const int* __restrict__ deg, int* __restrict__ off, int n){
  __shared__ int carry;
  __shared__ int buf[1024];
  if (threadIdx.x == 0) carry = 0;
  __syncthreads();
  for (int base = 0; base < n; base += 1024){
    int i = base + threadIdx.x;
    int v = (i < n) ? deg[i] : 0;
    buf[threadIdx.x] = v; __syncthreads();
    for (int o = 1; o < 1024; o <<= 1){
      int t = (threadIdx.x >= o) ? buf[threadIdx.x - o] : 0;
      __syncthreads();
      buf[threadIdx.x] += t;
      __syncthreads();
    }
    if (i < n) off[i] = carry + buf[threadIdx.x] - v;   // exclusive
    __syncthreads();
    if (threadIdx.x == 1023) carry += buf[1023];
    __syncthreads();
  }
  if (threadIdx.x == 0) off[n] = carry;
}
__global__ void scatter_kernel(const int* __restrict__ src, const int* __restrict__ dst,
                               const int* __restrict__ et, const int* __restrict__ off,
                               int* __restrict__ cur, int* __restrict__ es_src, int* __restrict__ es_et, int E){
  int e = blockIdx.x * 256 + threadIdx.x;
  if (e >= E) return;
  int d = dst[e];
  int p = off[d] + atomicAdd(&cur[d], 1);
  es_src[p] = src[e];
  es_et[p]  = et[e];
}

// ---------- qdot[n][r], kdot[n][r] from bf16 input ----------
__global__ void qdot_kernel(const unsigned short* __restrict__ xb, const float* __restrict__ wq,
                            const float* __restrict__ wk, float* __restrict__ qdot,
                            float* __restrict__ kdot){
  int node = blockIdx.x, t = threadIdx.x;
  __shared__ float xrow[256];
  xrow[t] = b2f(xb[(size_t)node * 256 + t]);
  __syncthreads();
  int out_id = t >> 2, part = t & 3;
  const float* wrow = (out_id < 32) ? (wq + out_id * 256) : (wk + (out_id - 32) * 256);
  float s = 0.f;
  #pragma unroll 4
  for (int i = part * 64; i < part * 64 + 64; ++i) s += xrow[i] * wrow[i];
  s += __shfl_down(s, 2); s += __shfl_down(s, 1);
  if (!part){
    if (out_id < 32) qdot[node * 32 + out_id] = s;
    else             kdot[node * 32 + out_id - 32] = s;
  }
}

// ---------- per-node softmax over CSR in-edges (wave per node) ----------
__global__ void attn_kernel(const float* __restrict__ qdot, const float* __restrict__ kdot,
                            const int* __restrict__ off, const int* __restrict__ es_src,
                            const int* __restrict__ es_et, float* __restrict__ a, int n){
  int node = blockIdx.x * 4 + (threadIdx.x >> 6);
  int lane = threadIdx.x & 63;
  if (node >= n) return;
  int s0 = off[node], s1 = off[node + 1];
  float m = -1e30f;
  for (int j = s0 + lane; j < s1; j += 64){
    int sc = es_src[j], et = es_et[j];
    float z = qdot[node * 32 + et] + kdot[sc * 32 + et];
    z = (z > 0.f) ? z : 0.2f * z;          // leaky_relu 0.2
    a[j] = z;
    m = fmaxf(m, z);
  }
  #pragma unroll
  for (int o = 32; o; o >>= 1) m = fmaxf(m, __shfl_xor(m, o));
  float s = 0.f;
  for (int j = s0 + lane; j < s1; j += 64){
    float e = __expf(a[j] - m);
    a[j] = e; s += e;
  }
  #pragma unroll
  for (int o = 32; o; o >>= 1) s += __shfl_xor(s, o);
  float inv = 1.0f / (s + 1e-16f);
  for (int j = s0 + lane; j < s1; j += 64) a[j] *= inv;
}

// ---------- MFMA bf16 GEMM: C[m, r-slice, n] = A[m,:] @ Bt[r][n,:]^T ----------
// A: [M][256] bf16 (k contiguous). Bt: [R][256 n][256 k] bf16 (k contiguous).
// MODE 0: C = xt [M][R_][256];  MODE 1: C = out [M][256] with +bias.
template<int MODE>
__global__ __launch_bounds__(256) void gemm_kernel(
    const unsigned short* __restrict__ A, const unsigned short* __restrict__ Bt,
    unsigned short* __restrict__ C, const float* __restrict__ bias, int M){
  __shared__ unsigned short As[128 * 64];
  __shared__ unsigned short Bs[128 * 64];
  const int r     = blockIdx.z;
  const int mbase = blockIdx.y * 128;
  const int nbase = blockIdx.x * 128;
  const int tid  = threadIdx.x;
  const int lane = tid & 63;
  const int wid  = tid >> 6;
  const int wm = (wid >> 1) * 64, wn = (wid & 1) * 64;
  const int lg = lane >> 4, lr = lane & 15;
  const unsigned short* Brel = Bt + (size_t)r * 65536;

  f32x4 acc[4][4];
  #pragma unroll
  for (int i = 0; i < 4; ++i)
    #pragma unroll
    for (int j = 0; j < 4; ++j) acc[i][j] = (f32x4)0.0f;

  for (int kt = 0; kt < 4; ++kt){
    // stage A,B tiles: 1024 16B-chunks each; XOR-swizzled source, linear LDS dest
    #pragma unroll
    for (int q = 0; q < 4; ++q){
      int ci  = (q * 4 + wid) * 64 + lane;          // 0..1023
      int row = ci >> 3, p = ci & 7;
      int gch = p ^ (row & 7);
      int grow = mbase + row; if (grow >= M) grow = M - 1;
      const unsigned short* ga = A + (size_t)grow * 256 + kt * 64 + gch * 8;
      __builtin_amdgcn_global_load_lds((const __attribute__((address_space(1))) void*)ga,
          (__attribute__((address_space(3))) void*)(As + (size_t)(q * 4 + wid) * 512), 16, 0, 0);
      const unsigned short* gb = Brel + (size_t)(nbase + row) * 256 + kt * 64 + gch * 8;
      __builtin_amdgcn_global_load_lds((const __attribute__((address_space(1))) void*)gb,
          (__attribute__((address_space(3))) void*)(Bs + (size_t)(q * 4 + wid) * 512), 16, 0, 0);
    }
    __syncthreads();
    #pragma unroll
    for (int kk = 0; kk < 2; ++kk){
      bf16x8 af[4], bg[4];
      #pragma unroll
      for (int mi = 0; mi < 4; ++mi){
        int row = wm + mi * 16 + lr;
        int pc = (lg + kk * 4) ^ (row & 7);
        af[mi] = *(const bf16x8*)&As[row * 64 + pc * 8];
      }
      #pragma unroll
      for (int ni = 0; ni < 4; ++ni){
        int row = wn + ni * 16 + lr;
        int pc = (lg + kk * 4) ^ (row & 7);
        bg[ni] = *(const bf16x8*)&Bs[row * 64 + pc * 8];
      }
      #pragma unroll
      for (int mi = 0; mi < 4; ++mi)
        #pragma unroll
        for (int ni = 0; ni < 4; ++ni)
          acc[mi][ni] = __builtin_amdgcn_mfma_f32_16x16x32_bf16(af[mi], bg[ni], acc[mi][ni], 0, 0, 0);
    }
    __syncthreads();
  }
  // epilogue: C/D layout col=lane&15, row=(lane>>4)*4+reg  [m89-verified]
  #pragma unroll
  for (int mi = 0; mi < 4; ++mi){
    #pragma unroll
    for (int j = 0; j < 4; ++j){
      int rowm = mbase + wm + mi * 16 + lg * 4 + j;
      if (rowm >= M) continue;
      #pragma unroll
      for (int ni = 0; ni < 4; ++ni){
        int col = nbase + wn + ni * 16 + lr;
        float v = acc[mi][ni][j];
        if (MODE == 0) C[((size_t)rowm * R_ + r) * H_ + col] = f2b(v);
        else           C[(size_t)rowm * H_ + col] = f2b(v + bias[col]);
      }
    }
  }
}

// ---------- aggregation: h[n][t] = relu(sum_j a[j]*xt[src_j, et_j, t]) ----------
__global__ void aggregate_kernel(const unsigned short* __restrict__ xt, const float* __restrict__ a,
                                 const int* __restrict__ off, const int* __restrict__ es_src,
                                 const int* __restrict__ es_et, unsigned short* __restrict__ hout){
  int node = blockIdx.x, t = threadIdx.x;
  int s0 = off[node], s1 = off[node + 1];
  float acc = 0.f;
  for (int j = s0; j < s1; ++j){
    int sc = es_src[j], et = es_et[j];
    float av = a[j];
    acc += av * b2f(xt[((size_t)sc * R_ + et) * H_ + t]);
  }
  hout[(size_t)node * H_ + t] = f2b(fmaxf(acc, 0.f));
}

// ---------- TransE scoring (wave per edge) ----------
__global__ void score_kernel(const unsigned short* __restrict__ hb, const unsigned short* __restrict__ relb,
                             const int* __restrict__ src_a, const int* __restrict__ dst_a,
                             const int* __restrict__ et_a, float* __restrict__ out, int E){
  int e = blockIdx.x * 4 + (threadIdx.x >> 6);
  int lane = threadIdx.x & 63;
  if (e >= E) return;
  int s = src_a[e], d = dst_a[e], r = et_a[e];
  ushort4 a4 = ((const ushort4*)(hb + (size_t)s * H_))[lane];
  ushort4 b4 = ((const ushort4*)(hb + (size_t)d * H_))[lane];
  ushort4 r4 = ((const ushort4*)(relb + (size_t)r * H_))[lane];
  float sum = fabsf(b2f(a4.x) + b2f(r4.x) - b2f(b4.x))
            + fabsf(b2f(a4.y) + b2f(r4.y) - b2f(b4.y))
            + fabsf(b2f(a4.z) + b2f(r4.z) - b2f(b4.z))
            + fabsf(b2f(a4.w) + b2f(r4.w) - b2f(b4.w));
  #pragma unroll
  for (int o = 32; o; o >>= 1) sum += __shfl_xor(sum, o);
  if (!lane) out[e] = GAMMA_ - sum;
}

extern "C" void kernel_launch(void* const* d_in, const int* in_sizes, int n_in,
                              void* d_out, int out_size, void* d_ws, size_t ws_size,
                              hipStream_t stream){
  const float* x         = (const float*)d_in[0];
  const int*   edge_idx  = (const int*)d_in[1];
  const int*   edge_type = (const int*)d_in[2];
  const float* W1        = (const float*)d_in[3];
  const float* q1        = (const float*)d_in[4];
  const float* k1        = (const float*)d_in[5];
  const float* W2        = (const float*)d_in[6];
  const float* q2        = (const float*)d_in[7];
  const float* k2        = (const float*)d_in[8];
  const float* lin_w     = (const float*)d_in[9];
  const float* lin_b     = (const float*)d_in[10];
  const float* rel_bert  = (const float*)d_in[11];
  const float* rel_lin_w = (const float*)d_in[12];
  const float* rel_lin_b = (const float*)d_in[13];
  float* score = (float*)d_out;

  const int Nn = in_sizes[0] / H_;   // 10000
  const int E  = in_sizes[1] / 2;    // 320000
  const int* src_a = edge_idx;
  const int* dst_a = edge_idx + E;

  // workspace carve-up (256B aligned)
  char* ws = (char*)d_ws;
  size_t cur_off = 0;
  auto carve = [&](size_t bytes)->char*{
    char* p = ws + cur_off;
    cur_off += (bytes + 255) & ~(size_t)255;
    return p;
  };
  unsigned short* xt   = (unsigned short*)carve((size_t)Nn * R_ * H_ * 2);
  unsigned short* xb   = (unsigned short*)carve((size_t)Nn * H_ * 2);
  unsigned short* h1   = (unsigned short*)carve((size_t)Nn * H_ * 2);
  unsigned short* h2   = (unsigned short*)carve((size_t)Nn * H_ * 2);
  unsigned short* outb = (unsigned short*)carve((size_t)Nn * H_ * 2);
  unsigned short* Wt1  = (unsigned short*)carve((size_t)R_ * 65536 * 2);
  unsigned short* Wt2  = (unsigned short*)carve((size_t)R_ * 65536 * 2);
  unsigned short* linT = (unsigned short*)carve(65536 * 2);
  unsigned short* relb = (unsigned short*)carve(R_ * H_ * 2);
  float* wq1 = (float*)carve(R_ * H_ * 4);
  float* wk1 = (float*)carve(R_ * H_ * 4);
  float* wq2 = (float*)carve(R_ * H_ * 4);
  float* wk2 = (float*)carve(R_ * H_ * 4);
  float* qdot = (float*)carve((size_t)Nn * R_ * 4);
  float* kdot = (float*)carve((size_t)Nn * R_ * 4);
  int* deg    = (int*)carve((size_t)Nn * 4);
  int* curs   = (int*)carve((size_t)Nn * 4);
  int* offs   = (int*)carve((size_t)(Nn + 1) * 4);
  int* es_src = (int*)carve((size_t)E * 4);
  int* es_et  = (int*)carve((size_t)E * 4);
  float* attn = (float*)carve((size_t)E * 4);
  (void)ws_size; (void)n_in; (void)out_size;

  const int mt = (Nn + 127) / 128;

  // prep
  cvt_kernel<<<(Nn * H_ / 4 + 255) / 256, 256, 0, stream>>>(x, xb, Nn * H_ / 4);
  transw_kernel<<<dim3(8, 8, R_), dim3(32, 8), 0, stream>>>(W1, Wt1);
  transw_kernel<<<dim3(8, 8, R_), dim3(32, 8), 0, stream>>>(W2, Wt2);
  transw_kernel<<<dim3(8, 8, 1),  dim3(32, 8), 0, stream>>>(lin_w, linT);
  wqk_kernel<<<dim3(H_, R_), 64, 0, stream>>>(W1, q1, k1, wq1, wk1);
  wqk_kernel<<<dim3(H_, R_), 64, 0, stream>>>(W2, q2, k2, wq2, wk2);
  rel_kernel<<<R_, H_, 0, stream>>>(rel_bert, rel_lin_w, rel_lin_b, relb);

  // CSR (shared by both layers)
  hipMemsetAsync(deg,  0, (size_t)Nn * 4, stream);
  hipMemsetAsync(curs, 0, (size_t)Nn * 4, stream);
  hist_kernel<<<(E + 255) / 256, 256, 0, stream>>>(dst_a, deg, E);
  scan_kernel<<<1, 1024, 0, stream>>>(deg, offs, Nn);
  scatter_kernel<<<(E + 255) / 256, 256, 0, stream>>>(src_a, dst_a, edge_type, offs, curs, es_src, es_et, E);

  // ---- layer 1 ----
  gemm_kernel<0><<<dim3(2, mt, R_), 256, 0, stream>>>(xb, Wt1, xt, nullptr, Nn);
  qdot_kernel<<<Nn, 256, 0, stream>>>(xb, wq1, wk1, qdot, kdot);
  attn_kernel<<<(Nn + 3) / 4, 256, 0, stream>>>(qdot, kdot, offs, es_src, es_et, attn, Nn);
  aggregate_kernel<<<Nn, 256, 0, stream>>>(xt, attn, offs, es_src, es_et, h1);

  // ---- layer 2 ----
  gemm_kernel<0><<<dim3(2, mt, R_), 256, 0, stream>>>(h1, Wt2, xt, nullptr, Nn);
  qdot_kernel<<<Nn, 256, 0, stream>>>(h1, wq2, wk2, qdot, kdot);
  attn_kernel<<<(Nn + 3) / 4, 256, 0, stream>>>(qdot, kdot, offs, es_src, es_et, attn, Nn);
  aggregate_kernel<<<Nn, 256, 0, stream>>>(xt, attn, offs, es_src, es_et, h2);

  // ---- final linear + scoring ----
  gemm_kernel<1><<<dim3(2, mt, 1), 256, 0, stream>>>(h2, linT, outb, lin_b, Nn);
  score_kernel<<<(E + 3) / 4, 256, 0, stream>>>(outb, relb, src_a, dst_a, edge_type, score, E);
}

// Round 2
// 545.898 us; speedup vs baseline: 1.2311x; 1.2311x over previous
//
#include <hip/hip_runtime.h>
#include <hip/hip_bf16.h>
#include <stdint.h>

#define R_ 32
#define H_ 256
#define GAMMA_ 10.0f

typedef __attribute__((ext_vector_type(4))) float f32x4;
typedef __attribute__((ext_vector_type(8))) short bf16x8;

__device__ __forceinline__ unsigned short f2b(float f){
  union { float f; unsigned u; } v; v.f = f;
  unsigned r = v.u + 0x7FFFu + ((v.u >> 16) & 1u);
  return (unsigned short)(r >> 16);
}
__device__ __forceinline__ float b2f(unsigned short h){
  union { unsigned u; float f; } v; v.u = ((unsigned)h) << 16; return v.f;
}

// ---------- fp32 -> bf16 convert (vectorized) ----------
__global__ void cvt_kernel(const float* __restrict__ in, unsigned short* __restrict__ out, int n4){
  int i = blockIdx.x * 256 + threadIdx.x;
  if (i < n4){
    float4 v = ((const float4*)in)[i];
    ushort4 o; o.x=f2b(v.x); o.y=f2b(v.y); o.z=f2b(v.z); o.w=f2b(v.w);
    ((ushort4*)out)[i] = o;
  }
}

// ---------- transpose [256][256] fp32 -> [256][256] bf16 (per z-slice) ----------
__global__ void transw_kernel(const float* __restrict__ W, unsigned short* __restrict__ Wt){
  __shared__ float tile[32][33];
  int r = blockIdx.z;
  int i0 = blockIdx.x * 32, o0 = blockIdx.y * 32;
  const float* Wr = W + (size_t)r * 65536;
  for (int rr = threadIdx.y; rr < 32; rr += 8)
    tile[rr][threadIdx.x] = Wr[(size_t)(i0 + rr) * 256 + o0 + threadIdx.x];
  __syncthreads();
  unsigned short* Wtr = Wt + (size_t)r * 65536;
  for (int rr = threadIdx.y; rr < 32; rr += 8)
    Wtr[(size_t)(o0 + rr) * 256 + i0 + threadIdx.x] = f2b(tile[threadIdx.x][rr]);
}

// ---------- wqkT[i][out]: out<32 -> wq[out][i], out>=32 -> wk[out-32][i] ----------
// wq[r][i] = sum_o W[r][i][o]*q[r][o]
__global__ void wqk_kernel(const float* __restrict__ W, const float* __restrict__ q,
                           const float* __restrict__ k, float* __restrict__ wqkT){
  int i = blockIdx.x, r = blockIdx.y, lane = threadIdx.x;
  const float* row = W + ((size_t)r * 256 + i) * 256;
  float sq = 0.f, sk = 0.f;
  for (int o = lane; o < 256; o += 64){ float w = row[o]; sq += w * q[r*256+o]; sk += w * k[r*256+o]; }
  #pragma unroll
  for (int off = 32; off; off >>= 1){ sq += __shfl_xor(sq, off); sk += __shfl_xor(sk, off); }
  if (!lane){ wqkT[i * 64 + r] = sq; wqkT[i * 64 + 32 + r] = sk; }
}

// ---------- rel = relu(rel_bert @ rel_lin_w + b) -> bf16 [32][256] ----------
__global__ void rel_kernel(const float* __restrict__ rb, const float* __restrict__ rw,
                           const float* __restrict__ bias, unsigned short* __restrict__ relb){
  int r = blockIdx.x, h = threadIdx.x;
  float acc = bias[h];
  const float* br = rb + (size_t)r * 768;
  for (int i = 0; i < 768; ++i) acc += br[i] * rw[(size_t)i * 256 + h];
  relb[r*256 + h] = f2b(fmaxf(acc, 0.f));
}

// ---------- CSR build ----------
__global__ void hist_kernel(const int* __restrict__ dst, int* __restrict__ deg, int E){
  int e = blockIdx.x * 256 + threadIdx.x;
  if (e < E) atomicAdd(&deg[dst[e]], 1);
}
__global__ void scan_kernel(const int* __restrict__ deg, int* __restrict__ off, int n){
  __shared__ int carry;
  __shared__ int buf[1024];
  if (threadIdx.x == 0) carry = 0;
  __syncthreads();
  for (int base = 0; base < n; base += 1024){
    int i = base + threadIdx.x;
    int v = (i < n) ? deg[i] : 0;
    buf[threadIdx.x] = v; __syncthreads();
    for (int o = 1; o < 1024; o <<= 1){
      int t = (threadIdx.x >= o) ? buf[threadIdx.x - o] : 0;
      __syncthreads();
      buf[threadIdx.x] += t;
      __syncthreads();
    }
    if (i < n) off[i] = carry + buf[threadIdx.x] - v;   // exclusive
    __syncthreads();
    if (threadIdx.x == 1023) carry += buf[1023];
    __syncthreads();
  }
  if (threadIdx.x == 0) off[n] = carry;
}
__global__ void scatter_kernel(const int* __restrict__ src, const int* __restrict__ dst,
                               const int* __restrict__ et, const int* __restrict__ off,
                               int* __restrict__ cur, int* __restrict__ es_src, int* __restrict__ es_et, int E){
  int e = blockIdx.x * 256 + threadIdx.x;
  if (e >= E) return;
  int d = dst[e];
  int p = off[d] + atomicAdd(&cur[d], 1);
  es_src[p] = src[e];
  es_et[p]  = et[e];
}

// ---------- qdot[n][r], kdot[n][r]: wave per node, lane = output, coalesced wqkT ----------
__global__ void qdot_kernel(const unsigned short* __restrict__ xb, const float* __restrict__ wqkT,
                            float* __restrict__ qdot, float* __restrict__ kdot, int n){
  __shared__ float xrow[4][256];
  int w = threadIdx.x >> 6, lane = threadIdx.x & 63;
  int node = blockIdx.x * 4 + w;
  if (node >= n) return;
  ushort4 v = ((const ushort4*)(xb + (size_t)node * 256))[lane];
  float* xr = xrow[w];
  xr[lane * 4 + 0] = b2f(v.x);
  xr[lane * 4 + 1] = b2f(v.y);
  xr[lane * 4 + 2] = b2f(v.z);
  xr[lane * 4 + 3] = b2f(v.w);
  // same-wave LDS write->read: compiler inserts lgkmcnt wait; no barrier needed
  float acc = 0.f;
  #pragma unroll 8
  for (int kk = 0; kk < 256; ++kk)
    acc = fmaf(xr[kk], wqkT[kk * 64 + lane], acc);
  if (lane < 32) qdot[node * 32 + lane] = acc;
  else           kdot[node * 32 + lane - 32] = acc;
}

// ---------- per-node softmax over CSR in-edges (wave per node) ----------
__global__ void attn_kernel(const float* __restrict__ qdot, const float* __restrict__ kdot,
                            const int* __restrict__ off, const int* __restrict__ es_src,
                            const int* __restrict__ es_et, float* __restrict__ a, int n){
  int node = blockIdx.x * 4 + (threadIdx.x >> 6);
  int lane = threadIdx.x & 63;
  if (node >= n) return;
  int s0 = off[node], s1 = off[node + 1];
  float m = -1e30f;
  for (int j = s0 + lane; j < s1; j += 64){
    int sc = es_src[j], et = es_et[j];
    float z = qdot[node * 32 + et] + kdot[sc * 32 + et];
    z = (z > 0.f) ? z : 0.2f * z;          // leaky_relu 0.2
    a[j] = z;
    m = fmaxf(m, z);
  }
  #pragma unroll
  for (int o = 32; o; o >>= 1) m = fmaxf(m, __shfl_xor(m, o));
  float s = 0.f;
  for (int j = s0 + lane; j < s1; j += 64){
    float e = __expf(a[j] - m);
    a[j] = e; s += e;
  }
  #pragma unroll
  for (int o = 32; o; o >>= 1) s += __shfl_xor(s, o);
  float inv = 1.0f / (s + 1e-16f);
  for (int j = s0 + lane; j < s1; j += 64) a[j] *= inv;
}

// ---------- MFMA bf16 GEMM: C[m, r-slice, n] = A[m,:] @ Bt[r][n,:]^T ----------
// A: [M][256] bf16 (k contiguous). Bt: [R][256 n][256 k] bf16 (k contiguous).
// MODE 0: C = xt [M][R_][256];  MODE 1: C = out [M][256] with +bias.
template<int MODE>
__global__ __launch_bounds__(256) void gemm_kernel(
    const unsigned short* __restrict__ A, const unsigned short* __restrict__ Bt,
    unsigned short* __restrict__ C, const float* __restrict__ bias, int M){
  __shared__ unsigned short As[128 * 64];
  __shared__ unsigned short Bs[128 * 64];
  const int r     = blockIdx.z;
  const int mbase = blockIdx.y * 128;
  const int nbase = blockIdx.x * 128;
  const int tid  = threadIdx.x;
  const int lane = tid & 63;
  const int wid  = tid >> 6;
  const int wm = (wid >> 1) * 64, wn = (wid & 1) * 64;
  const int lg = lane >> 4, lr = lane & 15;
  const unsigned short* Brel = Bt + (size_t)r * 65536;

  f32x4 acc[4][4];
  #pragma unroll
  for (int i = 0; i < 4; ++i)
    #pragma unroll
    for (int j = 0; j < 4; ++j) acc[i][j] = (f32x4)0.0f;

  for (int kt = 0; kt < 4; ++kt){
    // stage A,B tiles: 1024 16B-chunks each; XOR-swizzled source, linear LDS dest
    #pragma unroll
    for (int q = 0; q < 4; ++q){
      int ci  = (q * 4 + wid) * 64 + lane;          // 0..1023
      int row = ci >> 3, p = ci & 7;
      int gch = p ^ (row & 7);
      int grow = mbase + row; if (grow >= M) grow = M - 1;
      const unsigned short* ga = A + (size_t)grow * 256 + kt * 64 + gch * 8;
      __builtin_amdgcn_global_load_lds((const __attribute__((address_space(1))) void*)ga,
          (__attribute__((address_space(3))) void*)(As + (size_t)(q * 4 + wid) * 512), 16, 0, 0);
      const unsigned short* gb = Brel + (size_t)(nbase + row) * 256 + kt * 64 + gch * 8;
      __builtin_amdgcn_global_load_lds((const __attribute__((address_space(1))) void*)gb,
          (__attribute__((address_space(3))) void*)(Bs + (size_t)(q * 4 + wid) * 512), 16, 0, 0);
    }
    __syncthreads();
    #pragma unroll
    for (int kk = 0; kk < 2; ++kk){
      bf16x8 af[4], bg[4];
      #pragma unroll
      for (int mi = 0; mi < 4; ++mi){
        int row = wm + mi * 16 + lr;
        int pc = (lg + kk * 4) ^ (row & 7);
        af[mi] = *(const bf16x8*)&As[row * 64 + pc * 8];
      }
      #pragma unroll
      for (int ni = 0; ni < 4; ++ni){
        int row = wn + ni * 16 + lr;
        int pc = (lg + kk * 4) ^ (row & 7);
        bg[ni] = *(const bf16x8*)&Bs[row * 64 + pc * 8];
      }
      #pragma unroll
      for (int mi = 0; mi < 4; ++mi)
        #pragma unroll
        for (int ni = 0; ni < 4; ++ni)
          acc[mi][ni] = __builtin_amdgcn_mfma_f32_16x16x32_bf16(af[mi], bg[ni], acc[mi][ni], 0, 0, 0);
    }
    __syncthreads();
  }
  // epilogue: C/D layout col=lane&15, row=(lane>>4)*4+reg  [m89-verified]
  #pragma unroll
  for (int mi = 0; mi < 4; ++mi){
    #pragma unroll
    for (int j = 0; j < 4; ++j){
      int rowm = mbase + wm + mi * 16 + lg * 4 + j;
      if (rowm >= M) continue;
      #pragma unroll
      for (int ni = 0; ni < 4; ++ni){
        int col = nbase + wn + ni * 16 + lr;
        float v = acc[mi][ni][j];
        if (MODE == 0) C[((size_t)rowm * R_ + r) * H_ + col] = f2b(v);
        else           C[(size_t)rowm * H_ + col] = f2b(v + bias[col]);
      }
    }
  }
}

// ---------- aggregation: h[n][t] = relu(sum_j a[j]*xt[src_j, et_j, t]) ----------
__global__ void aggregate_kernel(const unsigned short* __restrict__ xt, const float* __restrict__ a,
                                 const int* __restrict__ off, const int* __restrict__ es_src,
                                 const int* __restrict__ es_et, unsigned short* __restrict__ hout){
  int node = blockIdx.x, t = threadIdx.x;
  int s0 = off[node], s1 = off[node + 1];
  float acc = 0.f;
  for (int j = s0; j < s1; ++j){
    int sc = es_src[j], et = es_et[j];
    float av = a[j];
    acc += av * b2f(xt[((size_t)sc * R_ + et) * H_ + t]);
  }
  hout[(size_t)node * H_ + t] = f2b(fmaxf(acc, 0.f));
}

// ---------- TransE scoring (wave per edge) ----------
__global__ void score_kernel(const unsigned short* __restrict__ hb, const unsigned short* __restrict__ relb,
                             const int* __restrict__ src_a, const int* __restrict__ dst_a,
                             const int* __restrict__ et_a, float* __restrict__ out, int E){
  int e = blockIdx.x * 4 + (threadIdx.x >> 6);
  int lane = threadIdx.x & 63;
  if (e >= E) return;
  int s = src_a[e], d = dst_a[e], r = et_a[e];
  ushort4 a4 = ((const ushort4*)(hb + (size_t)s * H_))[lane];
  ushort4 b4 = ((const ushort4*)(hb + (size_t)d * H_))[lane];
  ushort4 r4 = ((const ushort4*)(relb + (size_t)r * H_))[lane];
  float sum = fabsf(b2f(a4.x) + b2f(r4.x) - b2f(b4.x))
            + fabsf(b2f(a4.y) + b2f(r4.y) - b2f(b4.y))
            + fabsf(b2f(a4.z) + b2f(r4.z) - b2f(b4.z))
            + fabsf(b2f(a4.w) + b2f(r4.w) - b2f(b4.w));
  #pragma unroll
  for (int o = 32; o; o >>= 1) sum += __shfl_xor(sum, o);
  if (!lane) out[e] = GAMMA_ - sum;
}

extern "C" void kernel_launch(void* const* d_in, const int* in_sizes, int n_in,
                              void* d_out, int out_size, void* d_ws, size_t ws_size,
                              hipStream_t stream){
  const float* x         = (const float*)d_in[0];
  const int*   edge_idx  = (const int*)d_in[1];
  const int*   edge_type = (const int*)d_in[2];
  const float* W1        = (const float*)d_in[3];
  const float* q1        = (const float*)d_in[4];
  const float* k1        = (const float*)d_in[5];
  const float* W2        = (const float*)d_in[6];
  const float* q2        = (const float*)d_in[7];
  const float* k2        = (const float*)d_in[8];
  const float* lin_w     = (const float*)d_in[9];
  const float* lin_b     = (const float*)d_in[10];
  const float* rel_bert  = (const float*)d_in[11];
  const float* rel_lin_w = (const float*)d_in[12];
  const float* rel_lin_b = (const float*)d_in[13];
  float* score = (float*)d_out;

  const int Nn = in_sizes[0] / H_;   // 10000
  const int E  = in_sizes[1] / 2;    // 320000
  const int* src_a = edge_idx;
  const int* dst_a = edge_idx + E;

  // workspace carve-up (256B aligned)
  char* ws = (char*)d_ws;
  size_t cur_off = 0;
  auto carve = [&](size_t bytes)->char*{
    char* p = ws + cur_off;
    cur_off += (bytes + 255) & ~(size_t)255;
    return p;
  };
  unsigned short* xt   = (unsigned short*)carve((size_t)Nn * R_ * H_ * 2);
  unsigned short* xb   = (unsigned short*)carve((size_t)Nn * H_ * 2);
  unsigned short* h1   = (unsigned short*)carve((size_t)Nn * H_ * 2);
  unsigned short* h2   = (unsigned short*)carve((size_t)Nn * H_ * 2);
  unsigned short* outb = (unsigned short*)carve((size_t)Nn * H_ * 2);
  unsigned short* Wt1  = (unsigned short*)carve((size_t)R_ * 65536 * 2);
  unsigned short* Wt2  = (unsigned short*)carve((size_t)R_ * 65536 * 2);
  unsigned short* linT = (unsigned short*)carve(65536 * 2);
  unsigned short* relb = (unsigned short*)carve(R_ * H_ * 2);
  float* wqkT1 = (float*)carve(64 * H_ * 4);
  float* wqkT2 = (float*)carve(64 * H_ * 4);
  float* qdot = (float*)carve((size_t)Nn * R_ * 4);
  float* kdot = (float*)carve((size_t)Nn * R_ * 4);
  int* deg    = (int*)carve((size_t)Nn * 4);
  int* curs   = (int*)carve((size_t)Nn * 4);
  int* offs   = (int*)carve((size_t)(Nn + 1) * 4);
  int* es_src = (int*)carve((size_t)E * 4);
  int* es_et  = (int*)carve((size_t)E * 4);
  float* attn = (float*)carve((size_t)E * 4);
  (void)ws_size; (void)n_in; (void)out_size;

  const int mt = (Nn + 127) / 128;

  // prep
  cvt_kernel<<<(Nn * H_ / 4 + 255) / 256, 256, 0, stream>>>(x, xb, Nn * H_ / 4);
  transw_kernel<<<dim3(8, 8, R_), dim3(32, 8), 0, stream>>>(W1, Wt1);
  transw_kernel<<<dim3(8, 8, R_), dim3(32, 8), 0, stream>>>(W2, Wt2);
  transw_kernel<<<dim3(8, 8, 1),  dim3(32, 8), 0, stream>>>(lin_w, linT);
  wqk_kernel<<<dim3(H_, R_), 64, 0, stream>>>(W1, q1, k1, wqkT1);
  wqk_kernel<<<dim3(H_, R_), 64, 0, stream>>>(W2, q2, k2, wqkT2);
  rel_kernel<<<R_, H_, 0, stream>>>(rel_bert, rel_lin_w, rel_lin_b, relb);

  // CSR (shared by both layers)
  hipMemsetAsync(deg,  0, (size_t)Nn * 4, stream);
  hipMemsetAsync(curs, 0, (size_t)Nn * 4, stream);
  hist_kernel<<<(E + 255) / 256, 256, 0, stream>>>(dst_a, deg, E);
  scan_kernel<<<1, 1024, 0, stream>>>(deg, offs, Nn);
  scatter_kernel<<<(E + 255) / 256, 256, 0, stream>>>(src_a, dst_a, edge_type, offs, curs, es_src, es_et, E);

  // ---- layer 1 ----
  gemm_kernel<0><<<dim3(2, mt, R_), 256, 0, stream>>>(xb, Wt1, xt, nullptr, Nn);
  qdot_kernel<<<(Nn + 3) / 4, 256, 0, stream>>>(xb, wqkT1, qdot, kdot, Nn);
  attn_kernel<<<(Nn + 3) / 4, 256, 0, stream>>>(qdot, kdot, offs, es_src, es_et, attn, Nn);
  aggregate_kernel<<<Nn, 256, 0, stream>>>(xt, attn, offs, es_src, es_et, h1);

  // ---- layer 2 ----
  gemm_kernel<0><<<dim3(2, mt, R_), 256, 0, stream>>>(h1, Wt2, xt, nullptr, Nn);
  qdot_kernel<<<(Nn + 3) / 4, 256, 0, stream>>>(h1, wqkT2, qdot, kdot, Nn);
  attn_kernel<<<(Nn + 3) / 4, 256, 0, stream>>>(qdot, kdot, offs, es_src, es_et, attn, Nn);
  aggregate_kernel<<<Nn, 256, 0, stream>>>(xt, attn, offs, es_src, es_et, h2);

  // ---- final linear + scoring ----
  gemm_kernel<1><<<dim3(2, mt, 1), 256, 0, stream>>>(h2, linT, outb, lin_b, Nn);
  score_kernel<<<(E + 3) / 4, 256, 0, stream>>>(outb, relb, src_a, dst_a, edge_type, score, E);
}

// Round 3
// 483.016 us; speedup vs baseline: 1.3914x; 1.1302x over previous
//
#include <hip/hip_runtime.h>
#include <hip/hip_bf16.h>
#include <stdint.h>

#define R_ 32
#define H_ 256
#define GAMMA_ 10.0f

typedef __attribute__((ext_vector_type(4))) float f32x4;
typedef __attribute__((ext_vector_type(8))) short bf16x8;

__device__ __forceinline__ unsigned short f2b(float f){
  union { float f; unsigned u; } v; v.f = f;
  unsigned r = v.u + 0x7FFFu + ((v.u >> 16) & 1u);
  return (unsigned short)(r >> 16);
}
__device__ __forceinline__ float b2f(unsigned short h){
  union { unsigned u; float f; } v; v.u = ((unsigned)h) << 16; return v.f;
}

// ---------- fp32 -> bf16 convert (vectorized) ----------
__global__ void cvt_kernel(const float* __restrict__ in, unsigned short* __restrict__ out, int n4){
  int i = blockIdx.x * 256 + threadIdx.x;
  if (i < n4){
    float4 v = ((const float4*)in)[i];
    ushort4 o; o.x=f2b(v.x); o.y=f2b(v.y); o.z=f2b(v.z); o.w=f2b(v.w);
    ((ushort4*)out)[i] = o;
  }
}

// ---------- transpose [256][256] fp32 -> [256][256] bf16 (per z-slice) ----------
__global__ void transw_kernel(const float* __restrict__ W, unsigned short* __restrict__ Wt){
  __shared__ float tile[32][33];
  int r = blockIdx.z;
  int i0 = blockIdx.x * 32, o0 = blockIdx.y * 32;
  const float* Wr = W + (size_t)r * 65536;
  for (int rr = threadIdx.y; rr < 32; rr += 8)
    tile[rr][threadIdx.x] = Wr[(size_t)(i0 + rr) * 256 + o0 + threadIdx.x];
  __syncthreads();
  unsigned short* Wtr = Wt + (size_t)r * 65536;
  for (int rr = threadIdx.y; rr < 32; rr += 8)
    Wtr[(size_t)(o0 + rr) * 256 + i0 + threadIdx.x] = f2b(tile[threadIdx.x][rr]);
}

// ---------- wqkT[i][out]: out<32 -> wq[out][i], out>=32 -> wk[out-32][i] ----------
__global__ void wqk_kernel(const float* __restrict__ W, const float* __restrict__ q,
                           const float* __restrict__ k, float* __restrict__ wqkT){
  int i = blockIdx.x, r = blockIdx.y, lane = threadIdx.x;
  const float* row = W + ((size_t)r * 256 + i) * 256;
  float sq = 0.f, sk = 0.f;
  for (int o = lane; o < 256; o += 64){ float w = row[o]; sq += w * q[r*256+o]; sk += w * k[r*256+o]; }
  #pragma unroll
  for (int off = 32; off; off >>= 1){ sq += __shfl_xor(sq, off); sk += __shfl_xor(sk, off); }
  if (!lane){ wqkT[i * 64 + r] = sq; wqkT[i * 64 + 32 + r] = sk; }
}

// ---------- rel = relu(rel_bert @ rel_lin_w + b) -> bf16 [32][256] ----------
__global__ void rel_kernel(const float* __restrict__ rb, const float* __restrict__ rw,
                           const float* __restrict__ bias, unsigned short* __restrict__ relb){
  int r = blockIdx.x, h = threadIdx.x;
  float acc = bias[h];
  const float* br = rb + (size_t)r * 768;
  for (int i = 0; i < 768; ++i) acc += br[i] * rw[(size_t)i * 256 + h];
  relb[r*256 + h] = f2b(fmaxf(acc, 0.f));
}

// ---------- CSR build ----------
__global__ void hist_kernel(const int* __restrict__ dst, int* __restrict__ deg, int E){
  int e = blockIdx.x * 256 + threadIdx.x;
  if (e < E) atomicAdd(&deg[dst[e]], 1);
}
__global__ void scan_kernel(const int* __restrict__ deg, int* __restrict__ off, int n){
  __shared__ int carry;
  __shared__ int buf[1024];
  if (threadIdx.x == 0) carry = 0;
  __syncthreads();
  for (int base = 0; base < n; base += 1024){
    int i = base + threadIdx.x;
    int v = (i < n) ? deg[i] : 0;
    buf[threadIdx.x] = v; __syncthreads();
    for (int o = 1; o < 1024; o <<= 1){
      int t = (threadIdx.x >= o) ? buf[threadIdx.x - o] : 0;
      __syncthreads();
      buf[threadIdx.x] += t;
      __syncthreads();
    }
    if (i < n) off[i] = carry + buf[threadIdx.x] - v;   // exclusive
    __syncthreads();
    if (threadIdx.x == 1023) carry += buf[1023];
    __syncthreads();
  }
  if (threadIdx.x == 0) off[n] = carry;
}
__global__ void scatter_kernel(const int* __restrict__ src, const int* __restrict__ dst,
                               const int* __restrict__ et, const int* __restrict__ off,
                               int* __restrict__ cur, int* __restrict__ es_src, int* __restrict__ es_et, int E){
  int e = blockIdx.x * 256 + threadIdx.x;
  if (e >= E) return;
  int d = dst[e];
  int p = off[d] + atomicAdd(&cur[d], 1);
  es_src[p] = src[e];
  es_et[p]  = et[e];
}

// ---------- qdot[n][r], kdot[n][r]: wave per node, lane = output, coalesced wqkT ----------
__global__ void qdot_kernel(const unsigned short* __restrict__ xb, const float* __restrict__ wqkT,
                            float* __restrict__ qdot, float* __restrict__ kdot, int n){
  __shared__ float xrow[4][256];
  int w = threadIdx.x >> 6, lane = threadIdx.x & 63;
  int node = blockIdx.x * 4 + w;
  if (node >= n) return;
  ushort4 v = ((const ushort4*)(xb + (size_t)node * 256))[lane];
  float* xr = xrow[w];
  xr[lane * 4 + 0] = b2f(v.x);
  xr[lane * 4 + 1] = b2f(v.y);
  xr[lane * 4 + 2] = b2f(v.z);
  xr[lane * 4 + 3] = b2f(v.w);
  float acc = 0.f;
  #pragma unroll 8
  for (int kk = 0; kk < 256; ++kk)
    acc = fmaf(xr[kk], wqkT[kk * 64 + lane], acc);
  if (lane < 32) qdot[node * 32 + lane] = acc;
  else           kdot[node * 32 + lane - 32] = acc;
}

// ---------- per-node softmax over CSR in-edges (wave per node) ----------
__global__ void attn_kernel(const float* __restrict__ qdot, const float* __restrict__ kdot,
                            const int* __restrict__ off, const int* __restrict__ es_src,
                            const int* __restrict__ es_et, float* __restrict__ a, int n){
  int node = blockIdx.x * 4 + (threadIdx.x >> 6);
  int lane = threadIdx.x & 63;
  if (node >= n) return;
  int s0 = off[node], s1 = off[node + 1];
  float m = -1e30f;
  for (int j = s0 + lane; j < s1; j += 64){
    int sc = es_src[j], et = es_et[j];
    float z = qdot[node * 32 + et] + kdot[sc * 32 + et];
    z = (z > 0.f) ? z : 0.2f * z;          // leaky_relu 0.2
    a[j] = z;
    m = fmaxf(m, z);
  }
  #pragma unroll
  for (int o = 32; o; o >>= 1) m = fmaxf(m, __shfl_xor(m, o));
  float s = 0.f;
  for (int j = s0 + lane; j < s1; j += 64){
    float e = __expf(a[j] - m);
    a[j] = e; s += e;
  }
  #pragma unroll
  for (int o = 32; o; o >>= 1) s += __shfl_xor(s, o);
  float inv = 1.0f / (s + 1e-16f);
  for (int j = s0 + lane; j < s1; j += 64) a[j] *= inv;
}

// ---------- MFMA bf16 GEMM with double-buffered prefetch ----------
// A: [M][256] bf16. Bt: [R][256 n][256 k] bf16 (k contiguous).
// grid.x = R*NB (r = bx/NB, nb = bx%NB) so A-panel-sharing blocks are adjacent.
// MODE 0: C = xt [M][R_][256];  MODE 1: C = out [M][256] with +bias.
template<int MODE>
__global__ __launch_bounds__(256) void gemm_kernel(
    const unsigned short* __restrict__ A, const unsigned short* __restrict__ Bt,
    unsigned short* __restrict__ C, const float* __restrict__ bias, int M, int NB){
  __shared__ unsigned short As[2][128 * 64];
  __shared__ unsigned short Bs[2][128 * 64];
  const int r     = blockIdx.x / NB;
  const int nbase = (blockIdx.x % NB) * 128;
  const int mbase = blockIdx.y * 128;
  const int tid  = threadIdx.x;
  const int lane = tid & 63;
  const int wid  = tid >> 6;
  const int wm = (wid >> 1) * 64, wn = (wid & 1) * 64;
  const int lg = lane >> 4, lr = lane & 15;
  const unsigned short* Brel = Bt + (size_t)r * 65536;

  // per-thread staging coords (16B chunk per thread per quarter)
  f32x4 acc[4][4];
  #pragma unroll
  for (int i = 0; i < 4; ++i)
    #pragma unroll
    for (int j = 0; j < 4; ++j) acc[i][j] = (f32x4)0.0f;

  auto stage = [&](int buf, int kt){
    #pragma unroll
    for (int q = 0; q < 4; ++q){
      int ci  = (q * 4 + wid) * 64 + lane;          // 0..1023
      int row = ci >> 3, p = ci & 7;
      int gch = p ^ (row & 7);                       // inverse-swizzled source
      int grow = mbase + row; if (grow >= M) grow = M - 1;
      const unsigned short* ga = A + (size_t)grow * 256 + kt * 64 + gch * 8;
      __builtin_amdgcn_global_load_lds((const __attribute__((address_space(1))) void*)ga,
          (__attribute__((address_space(3))) void*)(As[buf] + (size_t)(q * 4 + wid) * 512), 16, 0, 0);
      const unsigned short* gb = Brel + (size_t)(nbase + row) * 256 + kt * 64 + gch * 8;
      __builtin_amdgcn_global_load_lds((const __attribute__((address_space(1))) void*)gb,
          (__attribute__((address_space(3))) void*)(Bs[buf] + (size_t)(q * 4 + wid) * 512), 16, 0, 0);
    }
  };

  stage(0, 0);
  __syncthreads();                                   // drains prologue stage

  for (int kt = 0; kt < 4; ++kt){
    const int cur = kt & 1;
    if (kt < 3) stage(cur ^ 1, kt + 1);              // prefetch overlaps compute
    #pragma unroll
    for (int kk = 0; kk < 2; ++kk){
      bf16x8 af[4], bg[4];
      #pragma unroll
      for (int mi = 0; mi < 4; ++mi){
        int row = wm + mi * 16 + lr;
        int pc = (lg + kk * 4) ^ (row & 7);
        af[mi] = *(const bf16x8*)&As[cur][row * 64 + pc * 8];
      }
      #pragma unroll
      for (int ni = 0; ni < 4; ++ni){
        int row = wn + ni * 16 + lr;
        int pc = (lg + kk * 4) ^ (row & 7);
        bg[ni] = *(const bf16x8*)&Bs[cur][row * 64 + pc * 8];
      }
      #pragma unroll
      for (int mi = 0; mi < 4; ++mi)
        #pragma unroll
        for (int ni = 0; ni < 4; ++ni)
          acc[mi][ni] = __builtin_amdgcn_mfma_f32_16x16x32_bf16(af[mi], bg[ni], acc[mi][ni], 0, 0, 0);
    }
    __syncthreads();   // drains prefetch (vmcnt) + guards buffer reuse
  }

  // epilogue: C/D layout col=lane&15, row=(lane>>4)*4+reg  [m89-verified]
  #pragma unroll
  for (int mi = 0; mi < 4; ++mi){
    #pragma unroll
    for (int j = 0; j < 4; ++j){
      int rowm = mbase + wm + mi * 16 + lg * 4 + j;
      if (rowm >= M) continue;
      #pragma unroll
      for (int ni = 0; ni < 4; ++ni){
        int col = nbase + wn + ni * 16 + lr;
        float v = acc[mi][ni][j];
        if (MODE == 0) C[((size_t)rowm * R_ + r) * H_ + col] = f2b(v);
        else           C[(size_t)rowm * H_ + col] = f2b(v + bias[col]);
      }
    }
  }
}

// ---------- aggregation: wave per node, lane covers 4 cols (512B/row/instr) ----------
__global__ void aggregate_kernel(const unsigned short* __restrict__ xt, const float* __restrict__ a,
                                 const int* __restrict__ off, const int* __restrict__ es_src,
                                 const int* __restrict__ es_et, unsigned short* __restrict__ hout, int n){
  int w = threadIdx.x >> 6, lane = threadIdx.x & 63;
  int node = blockIdx.x * 4 + w;
  if (node >= n) return;
  int s0 = off[node], s1 = off[node + 1];
  float a0 = 0.f, a1 = 0.f, a2 = 0.f, a3 = 0.f;
  for (int j = s0; j < s1; ++j){
    int sc = es_src[j], et = es_et[j];
    float av = a[j];
    ushort4 v = ((const ushort4*)(xt + ((size_t)sc * R_ + et) * H_))[lane];
    a0 = fmaf(av, b2f(v.x), a0);
    a1 = fmaf(av, b2f(v.y), a1);
    a2 = fmaf(av, b2f(v.z), a2);
    a3 = fmaf(av, b2f(v.w), a3);
  }
  ushort4 o;
  o.x = f2b(fmaxf(a0, 0.f)); o.y = f2b(fmaxf(a1, 0.f));
  o.z = f2b(fmaxf(a2, 0.f)); o.w = f2b(fmaxf(a3, 0.f));
  ((ushort4*)(hout + (size_t)node * H_))[lane] = o;
}

// ---------- TransE scoring (wave per edge) ----------
__global__ void score_kernel(const unsigned short* __restrict__ hb, const unsigned short* __restrict__ relb,
                             const int* __restrict__ src_a, const int* __restrict__ dst_a,
                             const int* __restrict__ et_a, float* __restrict__ out, int E){
  int e = blockIdx.x * 4 + (threadIdx.x >> 6);
  int lane = threadIdx.x & 63;
  if (e >= E) return;
  int s = src_a[e], d = dst_a[e], r = et_a[e];
  ushort4 a4 = ((const ushort4*)(hb + (size_t)s * H_))[lane];
  ushort4 b4 = ((const ushort4*)(hb + (size_t)d * H_))[lane];
  ushort4 r4 = ((const ushort4*)(relb + (size_t)r * H_))[lane];
  float sum = fabsf(b2f(a4.x) + b2f(r4.x) - b2f(b4.x))
            + fabsf(b2f(a4.y) + b2f(r4.y) - b2f(b4.y))
            + fabsf(b2f(a4.z) + b2f(r4.z) - b2f(b4.z))
            + fabsf(b2f(a4.w) + b2f(r4.w) - b2f(b4.w));
  #pragma unroll
  for (int o = 32; o; o >>= 1) sum += __shfl_xor(sum, o);
  if (!lane) out[e] = GAMMA_ - sum;
}

extern "C" void kernel_launch(void* const* d_in, const int* in_sizes, int n_in,
                              void* d_out, int out_size, void* d_ws, size_t ws_size,
                              hipStream_t stream){
  const float* x         = (const float*)d_in[0];
  const int*   edge_idx  = (const int*)d_in[1];
  const int*   edge_type = (const int*)d_in[2];
  const float* W1        = (const float*)d_in[3];
  const float* q1        = (const float*)d_in[4];
  const float* k1        = (const float*)d_in[5];
  const float* W2        = (const float*)d_in[6];
  const float* q2        = (const float*)d_in[7];
  const float* k2        = (const float*)d_in[8];
  const float* lin_w     = (const float*)d_in[9];
  const float* lin_b     = (const float*)d_in[10];
  const float* rel_bert  = (const float*)d_in[11];
  const float* rel_lin_w = (const float*)d_in[12];
  const float* rel_lin_b = (const float*)d_in[13];
  float* score = (float*)d_out;

  const int Nn = in_sizes[0] / H_;   // 10000
  const int E  = in_sizes[1] / 2;    // 320000
  const int* src_a = edge_idx;
  const int* dst_a = edge_idx + E;

  // workspace carve-up (256B aligned)
  char* ws = (char*)d_ws;
  size_t cur_off = 0;
  auto carve = [&](size_t bytes)->char*{
    char* p = ws + cur_off;
    cur_off += (bytes + 255) & ~(size_t)255;
    return p;
  };
  unsigned short* xt   = (unsigned short*)carve((size_t)Nn * R_ * H_ * 2);
  unsigned short* xb   = (unsigned short*)carve((size_t)Nn * H_ * 2);
  unsigned short* h1   = (unsigned short*)carve((size_t)Nn * H_ * 2);
  unsigned short* h2   = (unsigned short*)carve((size_t)Nn * H_ * 2);
  unsigned short* outb = (unsigned short*)carve((size_t)Nn * H_ * 2);
  unsigned short* Wt1  = (unsigned short*)carve((size_t)R_ * 65536 * 2);
  unsigned short* Wt2  = (unsigned short*)carve((size_t)R_ * 65536 * 2);
  unsigned short* linT = (unsigned short*)carve(65536 * 2);
  unsigned short* relb = (unsigned short*)carve(R_ * H_ * 2);
  float* wqkT1 = (float*)carve(64 * H_ * 4);
  float* wqkT2 = (float*)carve(64 * H_ * 4);
  float* qdot = (float*)carve((size_t)Nn * R_ * 4);
  float* kdot = (float*)carve((size_t)Nn * R_ * 4);
  int* deg    = (int*)carve((size_t)Nn * 4);
  int* curs   = (int*)carve((size_t)Nn * 4);
  int* offs   = (int*)carve((size_t)(Nn + 1) * 4);
  int* es_src = (int*)carve((size_t)E * 4);
  int* es_et  = (int*)carve((size_t)E * 4);
  float* attn = (float*)carve((size_t)E * 4);
  (void)ws_size; (void)n_in; (void)out_size;

  const int mt = (Nn + 127) / 128;

  // prep
  cvt_kernel<<<(Nn * H_ / 4 + 255) / 256, 256, 0, stream>>>(x, xb, Nn * H_ / 4);
  transw_kernel<<<dim3(8, 8, R_), dim3(32, 8), 0, stream>>>(W1, Wt1);
  transw_kernel<<<dim3(8, 8, R_), dim3(32, 8), 0, stream>>>(W2, Wt2);
  transw_kernel<<<dim3(8, 8, 1),  dim3(32, 8), 0, stream>>>(lin_w, linT);
  wqk_kernel<<<dim3(H_, R_), 64, 0, stream>>>(W1, q1, k1, wqkT1);
  wqk_kernel<<<dim3(H_, R_), 64, 0, stream>>>(W2, q2, k2, wqkT2);
  rel_kernel<<<R_, H_, 0, stream>>>(rel_bert, rel_lin_w, rel_lin_b, relb);

  // CSR (shared by both layers)
  hipMemsetAsync(deg,  0, (size_t)Nn * 4, stream);
  hipMemsetAsync(curs, 0, (size_t)Nn * 4, stream);
  hist_kernel<<<(E + 255) / 256, 256, 0, stream>>>(dst_a, deg, E);
  scan_kernel<<<1, 1024, 0, stream>>>(deg, offs, Nn);
  scatter_kernel<<<(E + 255) / 256, 256, 0, stream>>>(src_a, dst_a, edge_type, offs, curs, es_src, es_et, E);

  // ---- layer 1 ----
  gemm_kernel<0><<<dim3(R_ * 2, mt), 256, 0, stream>>>(xb, Wt1, xt, nullptr, Nn, 2);
  qdot_kernel<<<(Nn + 3) / 4, 256, 0, stream>>>(xb, wqkT1, qdot, kdot, Nn);
  attn_kernel<<<(Nn + 3) / 4, 256, 0, stream>>>(qdot, kdot, offs, es_src, es_et, attn, Nn);
  aggregate_kernel<<<(Nn + 3) / 4, 256, 0, stream>>>(xt, attn, offs, es_src, es_et, h1, Nn);

  // ---- layer 2 ----
  gemm_kernel<0><<<dim3(R_ * 2, mt), 256, 0, stream>>>(h1, Wt2, xt, nullptr, Nn, 2);
  qdot_kernel<<<(Nn + 3) / 4, 256, 0, stream>>>(h1, wqkT2, qdot, kdot, Nn);
  attn_kernel<<<(Nn + 3) / 4, 256, 0, stream>>>(qdot, kdot, offs, es_src, es_et, attn, Nn);
  aggregate_kernel<<<(Nn + 3) / 4, 256, 0, stream>>>(xt, attn, offs, es_src, es_et, h2, Nn);

  // ---- final linear + scoring ----
  gemm_kernel<1><<<dim3(2, mt), 256, 0, stream>>>(h2, linT, outb, lin_b, Nn, 2);
  score_kernel<<<(E + 3) / 4, 256, 0, stream>>>(outb, relb, src_a, dst_a, edge_type, score, E);
}